// Round 19
// baseline (140.790 us; speedup 1.0000x reference)
//
#include <hip/hip_runtime.h>
#include <cmath>

#define BB 16
#define CC 512
#define HWH 4096
#define NH 8
#define DK 64
#define PL 128
#define NGC 4

typedef float fx4 __attribute__((ext_vector_type(4)));

__device__ __forceinline__ float wred_sum(float v){
#pragma unroll
  for (int m = 32; m >= 1; m >>= 1) v += __shfl_xor(v, m, 64);
  return v;
}

// ws float offsets
#define OFF_E     0            // [128][4096] = 524,288 (unnormalized exp)
#define OFF_PSUM  524288       // [16][8][32][4] = 16,384
#define OFF_PCTX  540672       // [4][16][8][512] = 262,144
#define OFF_KQV   802816       // [16][3][8][64] = 24,576
#define OFF_ADDT  827392       // [16][512] = 8,192

// ---------------- K1: logits + exp + per-tile sums (NO max-subtract) ----------
// grid 512 = (b, pt32); block 1024 = 16 waves (c-split, 32 ch) x 64 lanes
// (float2 of p, 128-position tile). 32 KB LDS -> 2 blocks/CU = 8 waves/SIMD.
__global__ __launch_bounds__(1024) void k_logexp(const float* __restrict__ x,
                                                 const float* __restrict__ cmw,
                                                 float* __restrict__ e,
                                                 float* __restrict__ psum) {
  __shared__ float lds[8 * NH * 64 * 2];   // 32 KB tree buffer (8 slots)
  int b = blockIdx.x >> 5, pt = blockIdx.x & 31;
  int t = threadIdx.x, cs = t >> 6, l = t & 63;
  int pbase = pt * 128;
  const float* xb = x + ((size_t)(b * CC + cs * 32)) * HWH + pbase + l * 2;
  const float* wb = cmw + cs * 32;
  float acc[NH][2];
#pragma unroll
  for (int n = 0; n < NH; n++) { acc[n][0] = 0.f; acc[n][1] = 0.f; }
#pragma unroll 8
  for (int c = 0; c < 32; c++) {
    float2 xv = *reinterpret_cast<const float2*>(xb + (size_t)c * HWH);
#pragma unroll
    for (int n = 0; n < NH; n++) {
      float wv = wb[n * CC + c];    // wave-uniform -> s_load
      acc[n][0] = fmaf(xv.x, wv, acc[n][0]);
      acc[n][1] = fmaf(xv.y, wv, acc[n][1]);
    }
  }
  // 4-level LDS tree reduce over 16 c-split waves
  auto stslot = [&](int s) {
#pragma unroll
    for (int n = 0; n < NH; n++) {
      lds[((s * NH + n) * 64 + l) * 2 + 0] = acc[n][0];
      lds[((s * NH + n) * 64 + l) * 2 + 1] = acc[n][1];
    }
  };
  auto ldslot = [&](int s) {
#pragma unroll
    for (int n = 0; n < NH; n++) {
      acc[n][0] += lds[((s * NH + n) * 64 + l) * 2 + 0];
      acc[n][1] += lds[((s * NH + n) * 64 + l) * 2 + 1];
    }
  };
  if (cs >= 8) stslot(cs - 8);
  __syncthreads();
  if (cs < 8) ldslot(cs);
  __syncthreads();
  if (cs >= 4 && cs < 8) stslot(cs - 4);
  __syncthreads();
  if (cs < 4) ldslot(cs);
  __syncthreads();
  if (cs == 2 || cs == 3) stslot(cs - 2);
  __syncthreads();
  if (cs < 2) ldslot(cs);
  __syncthreads();
  if (cs == 1) stslot(0);
  __syncthreads();
  if (cs == 0) {
    ldslot(0);
    int p0 = pbase + l * 2;      // even; p0&63 <= 62 so +1 never crosses a row
    float colf = (float)(p0 & 63);
    float rowf = (float)(p0 >> 6);
#pragma unroll
    for (int n = 0; n < NH; n++) {
      float e0 = expf(acc[n][0]);
      float e1 = expf(acc[n][1]);
      float2 ev = make_float2(e0, e1);
      *reinterpret_cast<float2*>(e + (size_t)(b * NH + n) * HWH + p0) = ev;
      float s  = e0 + e1;
      float sc = e0 * colf + e1 * (colf + 1.f);
      float sy = s * rowf;
      s = wred_sum(s); sc = wred_sum(sc); sy = wred_sum(sy);
      if (l == 0) {
        size_t base = (((size_t)(b * NH + n)) * 32 + pt) * 4;
        psum[base] = s; psum[base + 1] = sc; psum[base + 2] = sy;
      }
    }
  }
}

// ---------------- K2: context partials (reg-only), ng-split x4 ----------------
// pctx[ng][b][h][c] = sum_{n in quarter ng} x[b,c,n] * e[b,h,n]
// grid 1024 = b(16) x cg(16) x ng(4), block 512 = 8 waves -> 8 waves/SIMD.
__global__ __launch_bounds__(512) void k_context(const float* __restrict__ x,
                                                 const float* __restrict__ e,
                                                 float* __restrict__ pctx) {
  int bid = blockIdx.x;
  int ng = bid & 3;
  int cg = (bid >> 2) & 15;
  int b = bid >> 6;
  int w = threadIdx.x >> 6;
  int l = threadIdx.x & 63;
  int cbase = cg * 32 + w * 4;
  const float* xb = x + ((size_t)(b * CC + cbase)) * HWH + ng * 1024 + l * 4;
  const float* eb = e + (size_t)b * NH * HWH + ng * 1024 + l * 4;
  float acc[4][NH];
#pragma unroll
  for (int ci = 0; ci < 4; ci++)
#pragma unroll
    for (int h = 0; h < NH; h++) acc[ci][h] = 0.f;
#pragma unroll
  for (int ch = 0; ch < 4; ch++) {   // 4 chunks of 256 n
    int off = ch * 256;
    float4 ev[NH];
#pragma unroll
    for (int h = 0; h < NH; h++)
      ev[h] = *reinterpret_cast<const float4*>(eb + (size_t)h * HWH + off);
#pragma unroll
    for (int ci = 0; ci < 4; ci++) {
      float4 xv = *reinterpret_cast<const float4*>(xb + (size_t)ci * HWH + off);
#pragma unroll
      for (int h = 0; h < NH; h++) {
        float a = acc[ci][h];
        a = fmaf(xv.x, ev[h].x, a);
        a = fmaf(xv.y, ev[h].y, a);
        a = fmaf(xv.z, ev[h].z, a);
        a = fmaf(xv.w, ev[h].w, a);
        acc[ci][h] = a;
      }
    }
  }
#pragma unroll
  for (int ci = 0; ci < 4; ci++)
#pragma unroll
    for (int h = 0; h < NH; h++) acc[ci][h] = wred_sum(acc[ci][h]);
  if (l == 0) {
    float* op = pctx + ((size_t)(ng * BB + b) * NH) * CC + cbase;
#pragma unroll
    for (int h = 0; h < NH; h++)
#pragma unroll
      for (int ci = 0; ci < 4; ci++) op[h * CC + ci] = acc[ci][h];
  }
}

// ---------------- K3: kqv, wave-cooperative coalesced dots (grid 384) --------
__global__ __launch_bounds__(512) void k_kqv(const float* __restrict__ pctx,
    const float* __restrict__ psum,
    const float* __restrict__ k_w, const float* __restrict__ q_w,
    const float* __restrict__ v_w,
    const float* __restrict__ k_b, const float* __restrict__ q_b,
    const float* __restrict__ v_b,
    float* __restrict__ kqvbuf) {
  int bid = blockIdx.x;
  int b = bid / 24;
  int r = bid - b * 24;
  int j = r >> 3;
  int h = r & 7;
  int t = threadIdx.x, wv = t >> 6, l = t & 63;
  __shared__ float ctx[512];
  __shared__ float invS_s;
  if (t < 32) {
    float S = psum[(((size_t)(b * NH + h)) * 32 + t) * 4];
#pragma unroll
    for (int m = 16; m >= 1; m >>= 1) S += __shfl_xor(S, m, 64);
    if (t == 0) invS_s = 1.f / S;
  }
  __syncthreads();
  float inv = invS_s;
  size_t base = ((size_t)b * NH + h) * CC + t;
  float cval = 0.f;
#pragma unroll
  for (int g = 0; g < NGC; g++)
    cval += pctx[(size_t)g * BB * NH * CC + base];
  ctx[t] = cval * inv;
  __syncthreads();
  float4 c0 = *reinterpret_cast<const float4*>(&ctx[l * 8]);
  float4 c1 = *reinterpret_cast<const float4*>(&ctx[l * 8 + 4]);
  const float* wm = (j == 0) ? k_w : (j == 1) ? q_w : v_w;
  const float* bm = (j == 0) ? k_b : (j == 1) ? q_b : v_b;
#pragma unroll
  for (int i = 0; i < 8; i++) {
    int d = wv * 8 + i;
    const float* wr = wm + d * CC + l * 8;
    float4 w0 = *reinterpret_cast<const float4*>(wr);
    float4 w1 = *reinterpret_cast<const float4*>(wr + 4);
    float a = w0.x * c0.x + w0.y * c0.y + w0.z * c0.z + w0.w * c0.w
            + w1.x * c1.x + w1.y * c1.y + w1.z * c1.z + w1.w * c1.w;
    a = wred_sum(a);
    if (l == 0)
      kqvbuf[((size_t)(b * 3 + j) * NH + h) * DK + d] = a + bm[d];
  }
}

// ---------------- K4: geometry + head softmax + out_ctx + MLP (grid 128) -----
__global__ __launch_bounds__(512) void k_attn_mlp(const float* __restrict__ kqvbuf,
    const float* __restrict__ psum,
    const float* __restrict__ g_w, const float* __restrict__ g_b,
    const float* __restrict__ aw1, const float* __restrict__ ab1,
    const float* __restrict__ lng, const float* __restrict__ lnb,
    const float* __restrict__ aw2, const float* __restrict__ ab2,
    float* __restrict__ add_term) {
  int b = blockIdx.x >> 3;
  int slice = blockIdx.x & 7;
  int t = threadIdx.x;
  int wv = t >> 6, l = t & 63;
  __shared__ float kq[3][NH * 68];
  __shared__ float smn[NH][NH];
  __shared__ float cxl[NH], cyl[NH];
  __shared__ float oc[CC];
  __shared__ float ypre[PL];
  __shared__ float yl[PL];
  __shared__ float sr[2][2];

  if (t < 256) {
    int h = t >> 5, pt = t & 31;
    size_t base = (((size_t)(b * NH + h)) * 32 + pt) * 4;
    float S = psum[base], SC = psum[base + 1], SY = psum[base + 2];
#pragma unroll
    for (int m = 16; m >= 1; m >>= 1) {
      S += __shfl_xor(S, m, 64); SC += __shfl_xor(SC, m, 64); SY += __shfl_xor(SY, m, 64);
    }
    if ((t & 31) == 0) {
      cxl[h] = SC / (S * 64.f);
      cyl[h] = SY / (S * 64.f);
    }
  }
  {
    int h = t >> 6, d = t & 63;
#pragma unroll
    for (int j = 0; j < 3; j++)
      kq[j][h * 68 + d] = kqvbuf[(size_t)(b * 3 + j) * 512 + t];
  }
  __syncthreads();

  if (t < 64) {
    int m = t >> 3, n = t & 7;
    float dx = cxl[m] - cxl[n];
    float dy = cyl[m] - cyl[n];
    float pos[4] = { fmaxf(dx, 0.f), fmaxf(-dx, 0.f), fmaxf(dy, 0.f), fmaxf(-dy, 0.f) };
    float a = g_b[0];
#pragma unroll
    for (int p = 0; p < 4; p++) {
#pragma unroll
      for (int f = 0; f < 8; f++) {
        float dm = expf(-0.8634694098727671f * (float)f);  // 1000^(-f/8)
        float ang = 100.f * pos[p] * dm;
        a = fmaf(sinf(ang), g_w[p * 8 + f], a);
        a = fmaf(cosf(ang), g_w[32 + p * 8 + f], a);
      }
    }
    float wgl = logf(fmaxf(fmaxf(a, 0.f), 1e-6f));
    float dot = 0.f;
#pragma unroll
    for (int dd = 0; dd < DK; dd++)
      dot = fmaf(kq[0][m * 68 + dd], kq[1][n * 68 + dd], dot);
    smn[m][n] = dot * 0.125f + wgl;
  }
  __syncthreads();
  if (t < 8) {
    float mx = -1e30f;
#pragma unroll
    for (int m = 0; m < NH; m++) mx = fmaxf(mx, smn[m][t]);
    float ssum = 0.f; float ex[NH];
#pragma unroll
    for (int m = 0; m < NH; m++) { ex[m] = expf(smn[m][t] - mx); ssum += ex[m]; }
#pragma unroll
    for (int m = 0; m < NH; m++) smn[m][t] = ex[m] / ssum;
  }
  __syncthreads();
  {
    int n = t >> 6, d = t & 63;
    float a = 0.f;
#pragma unroll
    for (int m = 0; m < NH; m++) a = fmaf(smn[m][n], kq[2][m * 68 + d], a);
    oc[t] = a;
  }
  __syncthreads();
  {  // MLP1: wave-cooperative coalesced rows
    float4 o0 = *reinterpret_cast<const float4*>(&oc[l * 8]);
    float4 o1 = *reinterpret_cast<const float4*>(&oc[l * 8 + 4]);
#pragma unroll
    for (int i = 0; i < 16; i++) {
      int d = wv * 16 + i;
      const float* wr = aw1 + d * CC + l * 8;
      float4 w0 = *reinterpret_cast<const float4*>(wr);
      float4 w1 = *reinterpret_cast<const float4*>(wr + 4);
      float a = w0.x * o0.x + w0.y * o0.y + w0.z * o0.z + w0.w * o0.w
              + w1.x * o1.x + w1.y * o1.y + w1.z * o1.z + w1.w * o1.w;
      a = wred_sum(a);
      if (l == 0) ypre[d] = a + ab1[d];
    }
  }
  __syncthreads();
  float y = 0.f;
  if (t < PL) y = ypre[t];
  {
    float s  = (t < PL) ? y : 0.f;
    float sq = s * y;
    s = wred_sum(s); sq = wred_sum(sq);
    if (t < PL && l == 0) { sr[0][wv] = s; sr[1][wv] = sq; }
  }
  __syncthreads();
  {
    float mu = (sr[0][0] + sr[0][1]) * (1.f / 128.f);
    float var = (sr[1][0] + sr[1][1]) * (1.f / 128.f) - mu * mu;
    float rstd = rsqrtf(var + 1e-5f);
    if (t < PL) yl[t] = fmaxf((y - mu) * rstd * lng[t] + lnb[t], 0.f);
  }
  __syncthreads();
  {  // MLP2: float2 coalesced rows
    float2 yv = *reinterpret_cast<const float2*>(&yl[l * 2]);
#pragma unroll
    for (int i = 0; i < 8; i++) {
      int c = slice * 64 + wv * 8 + i;
      float2 w2 = *reinterpret_cast<const float2*>(aw2 + c * PL + l * 2);
      float a = w2.x * yv.x + w2.y * yv.y;
      a = wred_sum(a);
      if (l == 0) add_term[b * CC + c] = a + ab2[c];
    }
  }
}

// ---------------- K5: out = x + add_term[b][c], nontemporal out stores -------
__global__ __launch_bounds__(256) void k_add(const float* __restrict__ x,
                                             const float* __restrict__ add_term,
                                             float* __restrict__ out) {
  const fx4* x4 = reinterpret_cast<const fx4*>(x);
  fx4* o4 = reinterpret_cast<fx4*>(out);
  const size_t n4 = (size_t)BB * CC * HWH / 4;  // 8388608
  for (size_t i = (size_t)blockIdx.x * 256 + threadIdx.x; i < n4;
       i += (size_t)gridDim.x * 256) {
    fx4 v = x4[i];
    float a = add_term[i >> 10];
    v += a;
    __builtin_nontemporal_store(v, &o4[i]);
  }
}

extern "C" void kernel_launch(void* const* d_in, const int* in_sizes, int n_in,
                              void* d_out, int out_size, void* d_ws, size_t ws_size,
                              hipStream_t stream) {
  const float* x   = (const float*)d_in[0];
  const float* cmw = (const float*)d_in[1];
  // d_in[2] conv_mask_b: per-head constant -> softmax-invariant, unused
  const float* g_w = (const float*)d_in[3];
  const float* g_b = (const float*)d_in[4];
  const float* k_w = (const float*)d_in[5];
  const float* k_b = (const float*)d_in[6];
  const float* q_w = (const float*)d_in[7];
  const float* q_b = (const float*)d_in[8];
  const float* v_w = (const float*)d_in[9];
  const float* v_b = (const float*)d_in[10];
  const float* aw1 = (const float*)d_in[11];
  const float* ab1 = (const float*)d_in[12];
  const float* lng = (const float*)d_in[13];
  const float* lnb = (const float*)d_in[14];
  const float* aw2 = (const float*)d_in[15];
  const float* ab2 = (const float*)d_in[16];
  float* out = (float*)d_out;
  float* ws = (float*)d_ws;

  float* e    = ws + OFF_E;
  float* psum = ws + OFF_PSUM;
  float* pctx = ws + OFF_PCTX;
  float* kqvb = ws + OFF_KQV;
  float* addt = ws + OFF_ADDT;

  hipLaunchKernelGGL(k_logexp,   dim3(512),  dim3(1024), 0, stream, x, cmw, e, psum);
  hipLaunchKernelGGL(k_context,  dim3(1024), dim3(512),  0, stream, x, e, pctx);
  hipLaunchKernelGGL(k_kqv,      dim3(384),  dim3(512),  0, stream, pctx, psum,
                     k_w, q_w, v_w, k_b, q_b, v_b, kqvb);
  hipLaunchKernelGGL(k_attn_mlp, dim3(128),  dim3(512),  0, stream, kqvb, psum,
                     g_w, g_b, aw1, ab1, lng, lnb, aw2, ab2, addt);
  hipLaunchKernelGGL(k_add,      dim3(2048), dim3(256),  0, stream, x, addt, out);
}

// Round 20
// 133.651 us; speedup vs baseline: 1.0534x; 1.0534x over previous
//
#include <hip/hip_runtime.h>
#include <cmath>

#define BB 16
#define CC 512
#define HWH 4096
#define NH 8
#define DK 64
#define PL 128
#define NGC 4

typedef float fx4 __attribute__((ext_vector_type(4)));

__device__ __forceinline__ float wred_sum(float v){
#pragma unroll
  for (int m = 32; m >= 1; m >>= 1) v += __shfl_xor(v, m, 64);
  return v;
}

// ws float offsets
#define OFF_E     0            // [128][4096] = 524,288 (unnormalized exp)
#define OFF_PSUM  524288       // [16][8][16][4] = 8,192
#define OFF_PCTX  532480       // [4][16][8][512] = 262,144
#define OFF_KQV   794624       // [16][3][8][64] = 24,576
#define OFF_ADDT  819200       // [16][512] = 8,192

// ---------------- K1: logits + exp + per-tile sums (NO max-subtract) ----------
// grid 256 = (b, pt); block 1024 = 16 waves (c-split, 32 ch each) x 64 lanes.
__global__ __launch_bounds__(1024) void k_logexp(const float* __restrict__ x,
                                                 const float* __restrict__ cmw,
                                                 float* __restrict__ e,
                                                 float* __restrict__ psum) {
  __shared__ float lds[8 * NH * 64 * 4];   // 64 KB tree buffer (8 slots)
  int b = blockIdx.x >> 4, pt = blockIdx.x & 15;
  int t = threadIdx.x, cs = t >> 6, l = t & 63;
  int pbase = pt * 256;
  const float* xb = x + ((size_t)(b * CC + cs * 32)) * HWH + pbase + l * 4;
  const float* wb = cmw + cs * 32;
  float acc[NH][4];
#pragma unroll
  for (int n = 0; n < NH; n++)
#pragma unroll
    for (int k = 0; k < 4; k++) acc[n][k] = 0.f;
#pragma unroll 8
  for (int c = 0; c < 32; c++) {
    float4 xv = *reinterpret_cast<const float4*>(xb + (size_t)c * HWH);
#pragma unroll
    for (int n = 0; n < NH; n++) {
      float wv = wb[n * CC + c];    // wave-uniform -> s_load
      acc[n][0] = fmaf(xv.x, wv, acc[n][0]);
      acc[n][1] = fmaf(xv.y, wv, acc[n][1]);
      acc[n][2] = fmaf(xv.z, wv, acc[n][2]);
      acc[n][3] = fmaf(xv.w, wv, acc[n][3]);
    }
  }
  // 4-level LDS tree reduce over 16 c-split waves
  auto stslot = [&](int s) {
#pragma unroll
    for (int n = 0; n < NH; n++)
#pragma unroll
      for (int k = 0; k < 4; k++)
        lds[((s * NH + n) * 64 + l) * 4 + k] = acc[n][k];
  };
  auto ldslot = [&](int s) {
#pragma unroll
    for (int n = 0; n < NH; n++)
#pragma unroll
      for (int k = 0; k < 4; k++)
        acc[n][k] += lds[((s * NH + n) * 64 + l) * 4 + k];
  };
  if (cs >= 8) stslot(cs - 8);
  __syncthreads();
  if (cs < 8) ldslot(cs);
  __syncthreads();
  if (cs >= 4 && cs < 8) stslot(cs - 4);
  __syncthreads();
  if (cs < 4) ldslot(cs);
  __syncthreads();
  if (cs == 2 || cs == 3) stslot(cs - 2);
  __syncthreads();
  if (cs < 2) ldslot(cs);
  __syncthreads();
  if (cs == 1) stslot(0);
  __syncthreads();
  if (cs == 0) {
    ldslot(0);
    int p0 = pbase + l * 4;
    float colf = (float)(p0 & 63);
    float rowf = (float)(p0 >> 6);
#pragma unroll
    for (int n = 0; n < NH; n++) {
      float4 ev;
      ev.x = expf(acc[n][0]); ev.y = expf(acc[n][1]);
      ev.z = expf(acc[n][2]); ev.w = expf(acc[n][3]);
      *reinterpret_cast<float4*>(e + (size_t)(b * NH + n) * HWH + p0) = ev;
      float s  = ev.x + ev.y + ev.z + ev.w;
      float sc = ev.x * colf + ev.y * (colf + 1.f) + ev.z * (colf + 2.f) + ev.w * (colf + 3.f);
      float sy = s * rowf;
      s = wred_sum(s); sc = wred_sum(sc); sy = wred_sum(sy);
      if (l == 0) {
        size_t base = (((size_t)(b * NH + n)) * 16 + pt) * 4;
        psum[base] = s; psum[base + 1] = sc; psum[base + 2] = sy;
      }
    }
  }
}

// ---------------- K2: context partials (reg-only), ng-split x4 ----------------
// pctx[ng][b][h][c] = sum_{n in quarter ng} x[b,c,n] * e[b,h,n]
// grid 1024 = b(16) x cg(16) x ng(4), block 512 = 8 waves -> 8 waves/SIMD.
__global__ __launch_bounds__(512) void k_context(const float* __restrict__ x,
                                                 const float* __restrict__ e,
                                                 float* __restrict__ pctx) {
  int bid = blockIdx.x;
  int ng = bid & 3;
  int cg = (bid >> 2) & 15;
  int b = bid >> 6;
  int w = threadIdx.x >> 6;
  int l = threadIdx.x & 63;
  int cbase = cg * 32 + w * 4;
  const float* xb = x + ((size_t)(b * CC + cbase)) * HWH + ng * 1024 + l * 4;
  const float* eb = e + (size_t)b * NH * HWH + ng * 1024 + l * 4;
  float acc[4][NH];
#pragma unroll
  for (int ci = 0; ci < 4; ci++)
#pragma unroll
    for (int h = 0; h < NH; h++) acc[ci][h] = 0.f;
#pragma unroll
  for (int ch = 0; ch < 4; ch++) {   // 4 chunks of 256 n
    int off = ch * 256;
    float4 ev[NH];
#pragma unroll
    for (int h = 0; h < NH; h++)
      ev[h] = *reinterpret_cast<const float4*>(eb + (size_t)h * HWH + off);
#pragma unroll
    for (int ci = 0; ci < 4; ci++) {
      float4 xv = *reinterpret_cast<const float4*>(xb + (size_t)ci * HWH + off);
#pragma unroll
      for (int h = 0; h < NH; h++) {
        float a = acc[ci][h];
        a = fmaf(xv.x, ev[h].x, a);
        a = fmaf(xv.y, ev[h].y, a);
        a = fmaf(xv.z, ev[h].z, a);
        a = fmaf(xv.w, ev[h].w, a);
        acc[ci][h] = a;
      }
    }
  }
#pragma unroll
  for (int ci = 0; ci < 4; ci++)
#pragma unroll
    for (int h = 0; h < NH; h++) acc[ci][h] = wred_sum(acc[ci][h]);
  if (l == 0) {
    float* op = pctx + ((size_t)(ng * BB + b) * NH) * CC + cbase;
#pragma unroll
    for (int h = 0; h < NH; h++)
#pragma unroll
      for (int ci = 0; ci < 4; ci++) op[h * CC + ci] = acc[ci][h];
  }
}

// ---------------- K3: kqv, wave-cooperative coalesced dots (grid 384) --------
__global__ __launch_bounds__(512) void k_kqv(const float* __restrict__ pctx,
    const float* __restrict__ psum,
    const float* __restrict__ k_w, const float* __restrict__ q_w,
    const float* __restrict__ v_w,
    const float* __restrict__ k_b, const float* __restrict__ q_b,
    const float* __restrict__ v_b,
    float* __restrict__ kqvbuf) {
  int bid = blockIdx.x;
  int b = bid / 24;
  int r = bid - b * 24;
  int j = r >> 3;
  int h = r & 7;
  int t = threadIdx.x, wv = t >> 6, l = t & 63;
  __shared__ float ctx[512];
  __shared__ float invS_s;
  if (t < 16) {
    float S = psum[(((size_t)(b * NH + h)) * 16 + t) * 4];
#pragma unroll
    for (int m = 8; m >= 1; m >>= 1) S += __shfl_xor(S, m, 64);
    if (t == 0) invS_s = 1.f / S;
  }
  __syncthreads();
  float inv = invS_s;
  size_t base = ((size_t)b * NH + h) * CC + t;
  float cval = 0.f;
#pragma unroll
  for (int g = 0; g < NGC; g++)
    cval += pctx[(size_t)g * BB * NH * CC + base];
  ctx[t] = cval * inv;
  __syncthreads();
  float4 c0 = *reinterpret_cast<const float4*>(&ctx[l * 8]);
  float4 c1 = *reinterpret_cast<const float4*>(&ctx[l * 8 + 4]);
  const float* wm = (j == 0) ? k_w : (j == 1) ? q_w : v_w;
  const float* bm = (j == 0) ? k_b : (j == 1) ? q_b : v_b;
#pragma unroll
  for (int i = 0; i < 8; i++) {
    int d = wv * 8 + i;
    const float* wr = wm + d * CC + l * 8;
    float4 w0 = *reinterpret_cast<const float4*>(wr);
    float4 w1 = *reinterpret_cast<const float4*>(wr + 4);
    float a = w0.x * c0.x + w0.y * c0.y + w0.z * c0.z + w0.w * c0.w
            + w1.x * c1.x + w1.y * c1.y + w1.z * c1.z + w1.w * c1.w;
    a = wred_sum(a);
    if (l == 0)
      kqvbuf[((size_t)(b * 3 + j) * NH + h) * DK + d] = a + bm[d];
  }
}

// ---------------- K4: geometry + head softmax + out_ctx + MLP (grid 128) -----
__global__ __launch_bounds__(512) void k_attn_mlp(const float* __restrict__ kqvbuf,
    const float* __restrict__ psum,
    const float* __restrict__ g_w, const float* __restrict__ g_b,
    const float* __restrict__ aw1, const float* __restrict__ ab1,
    const float* __restrict__ lng, const float* __restrict__ lnb,
    const float* __restrict__ aw2, const float* __restrict__ ab2,
    float* __restrict__ add_term) {
  int b = blockIdx.x >> 3;
  int slice = blockIdx.x & 7;
  int t = threadIdx.x;
  int wv = t >> 6, l = t & 63;
  __shared__ float kq[3][NH * 68];
  __shared__ float smn[NH][NH];
  __shared__ float cxl[NH], cyl[NH];
  __shared__ float oc[CC];
  __shared__ float ypre[PL];
  __shared__ float yl[PL];
  __shared__ float sr[2][2];

  if (t < 128) {
    int h = t >> 4, pt = t & 15;
    size_t base = (((size_t)(b * NH + h)) * 16 + pt) * 4;
    float S = psum[base], SC = psum[base + 1], SY = psum[base + 2];
#pragma unroll
    for (int m = 8; m >= 1; m >>= 1) {
      S += __shfl_xor(S, m, 64); SC += __shfl_xor(SC, m, 64); SY += __shfl_xor(SY, m, 64);
    }
    if ((t & 15) == 0) {
      cxl[h] = SC / (S * 64.f);
      cyl[h] = SY / (S * 64.f);
    }
  }
  {
    int h = t >> 6, d = t & 63;
#pragma unroll
    for (int j = 0; j < 3; j++)
      kq[j][h * 68 + d] = kqvbuf[(size_t)(b * 3 + j) * 512 + t];
  }
  __syncthreads();

  if (t < 64) {
    int m = t >> 3, n = t & 7;
    float dx = cxl[m] - cxl[n];
    float dy = cyl[m] - cyl[n];
    float pos[4] = { fmaxf(dx, 0.f), fmaxf(-dx, 0.f), fmaxf(dy, 0.f), fmaxf(-dy, 0.f) };
    float a = g_b[0];
#pragma unroll
    for (int p = 0; p < 4; p++) {
#pragma unroll
      for (int f = 0; f < 8; f++) {
        float dm = expf(-0.8634694098727671f * (float)f);  // 1000^(-f/8)
        float ang = 100.f * pos[p] * dm;
        a = fmaf(sinf(ang), g_w[p * 8 + f], a);
        a = fmaf(cosf(ang), g_w[32 + p * 8 + f], a);
      }
    }
    float wgl = logf(fmaxf(fmaxf(a, 0.f), 1e-6f));
    float dot = 0.f;
#pragma unroll
    for (int dd = 0; dd < DK; dd++)
      dot = fmaf(kq[0][m * 68 + dd], kq[1][n * 68 + dd], dot);
    smn[m][n] = dot * 0.125f + wgl;
  }
  __syncthreads();
  if (t < 8) {
    float mx = -1e30f;
#pragma unroll
    for (int m = 0; m < NH; m++) mx = fmaxf(mx, smn[m][t]);
    float ssum = 0.f; float ex[NH];
#pragma unroll
    for (int m = 0; m < NH; m++) { ex[m] = expf(smn[m][t] - mx); ssum += ex[m]; }
#pragma unroll
    for (int m = 0; m < NH; m++) smn[m][t] = ex[m] / ssum;
  }
  __syncthreads();
  {
    int n = t >> 6, d = t & 63;
    float a = 0.f;
#pragma unroll
    for (int m = 0; m < NH; m++) a = fmaf(smn[m][n], kq[2][m * 68 + d], a);
    oc[t] = a;
  }
  __syncthreads();
  {  // MLP1: wave-cooperative coalesced rows
    float4 o0 = *reinterpret_cast<const float4*>(&oc[l * 8]);
    float4 o1 = *reinterpret_cast<const float4*>(&oc[l * 8 + 4]);
#pragma unroll
    for (int i = 0; i < 16; i++) {
      int d = wv * 16 + i;
      const float* wr = aw1 + d * CC + l * 8;
      float4 w0 = *reinterpret_cast<const float4*>(wr);
      float4 w1 = *reinterpret_cast<const float4*>(wr + 4);
      float a = w0.x * o0.x + w0.y * o0.y + w0.z * o0.z + w0.w * o0.w
              + w1.x * o1.x + w1.y * o1.y + w1.z * o1.z + w1.w * o1.w;
      a = wred_sum(a);
      if (l == 0) ypre[d] = a + ab1[d];
    }
  }
  __syncthreads();
  float y = 0.f;
  if (t < PL) y = ypre[t];
  {
    float s  = (t < PL) ? y : 0.f;
    float sq = s * y;
    s = wred_sum(s); sq = wred_sum(sq);
    if (t < PL && l == 0) { sr[0][wv] = s; sr[1][wv] = sq; }
  }
  __syncthreads();
  {
    float mu = (sr[0][0] + sr[0][1]) * (1.f / 128.f);
    float var = (sr[1][0] + sr[1][1]) * (1.f / 128.f) - mu * mu;
    float rstd = rsqrtf(var + 1e-5f);
    if (t < PL) yl[t] = fmaxf((y - mu) * rstd * lng[t] + lnb[t], 0.f);
  }
  __syncthreads();
  {  // MLP2: float2 coalesced rows
    float2 yv = *reinterpret_cast<const float2*>(&yl[l * 2]);
#pragma unroll
    for (int i = 0; i < 8; i++) {
      int c = slice * 64 + wv * 8 + i;
      float2 w2 = *reinterpret_cast<const float2*>(aw2 + c * PL + l * 2);
      float a = w2.x * yv.x + w2.y * yv.y;
      a = wred_sum(a);
      if (l == 0) add_term[b * CC + c] = a + ab2[c];
    }
  }
}

// ---------------- K5: out = x + add_term[b][c], nontemporal out stores -------
__global__ __launch_bounds__(256) void k_add(const float* __restrict__ x,
                                             const float* __restrict__ add_term,
                                             float* __restrict__ out) {
  const fx4* x4 = reinterpret_cast<const fx4*>(x);
  fx4* o4 = reinterpret_cast<fx4*>(out);
  const size_t n4 = (size_t)BB * CC * HWH / 4;  // 8388608
  for (size_t i = (size_t)blockIdx.x * 256 + threadIdx.x; i < n4;
       i += (size_t)gridDim.x * 256) {
    fx4 v = x4[i];
    float a = add_term[i >> 10];
    v += a;
    __builtin_nontemporal_store(v, &o4[i]);
  }
}

extern "C" void kernel_launch(void* const* d_in, const int* in_sizes, int n_in,
                              void* d_out, int out_size, void* d_ws, size_t ws_size,
                              hipStream_t stream) {
  const float* x   = (const float*)d_in[0];
  const float* cmw = (const float*)d_in[1];
  // d_in[2] conv_mask_b: per-head constant -> softmax-invariant, unused
  const float* g_w = (const float*)d_in[3];
  const float* g_b = (const float*)d_in[4];
  const float* k_w = (const float*)d_in[5];
  const float* k_b = (const float*)d_in[6];
  const float* q_w = (const float*)d_in[7];
  const float* q_b = (const float*)d_in[8];
  const float* v_w = (const float*)d_in[9];
  const float* v_b = (const float*)d_in[10];
  const float* aw1 = (const float*)d_in[11];
  const float* ab1 = (const float*)d_in[12];
  const float* lng = (const float*)d_in[13];
  const float* lnb = (const float*)d_in[14];
  const float* aw2 = (const float*)d_in[15];
  const float* ab2 = (const float*)d_in[16];
  float* out = (float*)d_out;
  float* ws = (float*)d_ws;

  float* e    = ws + OFF_E;
  float* psum = ws + OFF_PSUM;
  float* pctx = ws + OFF_PCTX;
  float* kqvb = ws + OFF_KQV;
  float* addt = ws + OFF_ADDT;

  hipLaunchKernelGGL(k_logexp,   dim3(256),  dim3(1024), 0, stream, x, cmw, e, psum);
  hipLaunchKernelGGL(k_context,  dim3(1024), dim3(512),  0, stream, x, e, pctx);
  hipLaunchKernelGGL(k_kqv,      dim3(384),  dim3(512),  0, stream, pctx, psum,
                     k_w, q_w, v_w, k_b, q_b, v_b, kqvb);
  hipLaunchKernelGGL(k_attn_mlp, dim3(128),  dim3(512),  0, stream, kqvb, psum,
                     g_w, g_b, aw1, ab1, lng, lnb, aw2, ab2, addt);
  hipLaunchKernelGGL(k_add,      dim3(2048), dim3(256),  0, stream, x, addt, out);
}